// Round 12
// baseline (195.473 us; speedup 1.0000x reference)
//
#include <hip/hip_runtime.h>
#include <hip/hip_bf16.h>
#include <cstdint>
#include <cstddef>

// Problem constants: B=32, N=768, D=768
#define BN_ROWS 24576
#define DD 768
#define BE (768*768)

typedef __attribute__((ext_vector_type(8))) short bf16x8;
typedef __attribute__((ext_vector_type(4))) float f32x4;
typedef __attribute__((ext_vector_type(8))) unsigned short u16x8;

static __device__ __forceinline__ unsigned short f2bf(float f) {
  unsigned int u = __builtin_bit_cast(unsigned int, f);
  unsigned int lsb = (u >> 16) & 1u;
  u += 0x7fffu + lsb;
  return (unsigned short)(u >> 16);
}

static __device__ __forceinline__ u16x8 pack8(float4 a, float4 b) {
  u16x8 o;
  o[0] = f2bf(a.x); o[1] = f2bf(a.y); o[2] = f2bf(a.z); o[3] = f2bf(a.w);
  o[4] = f2bf(b.x); o[5] = f2bf(b.y); o[6] = f2bf(b.z); o[7] = f2bf(b.w);
  return o;
}

// ---------------- convertX: 16B loads AND 16B stores ----------------
#define CXB 2304
#define CXS (CXB * 256)       // 589824 units stride

__global__ __launch_bounds__(256) void convertX(const float* __restrict__ x,
                                                unsigned short* __restrict__ xb) {
  const int u0 = blockIdx.x * 256 + threadIdx.x;
  const float4* in = reinterpret_cast<const float4*>(x);
  u16x8* outp = reinterpret_cast<u16x8*>(xb);
  float4 v[8];
  #pragma unroll
  for (int j = 0; j < 4; ++j) {
    v[2 * j]     = in[(size_t)(u0 + j * CXS) * 2];
    v[2 * j + 1] = in[(size_t)(u0 + j * CXS) * 2 + 1];
  }
  #pragma unroll
  for (int j = 0; j < 4; ++j)
    outp[u0 + j * CXS] = pack8(v[2 * j], v[2 * j + 1]);
}

// ---------------- prep2: adjNorm (16B stores) + convertWT ----------------
#define ANB 3072

__global__ __launch_bounds__(256) void prep2(const float* __restrict__ adj,
                                             const float* __restrict__ Wl,
                                             const float* __restrict__ Wl1,
                                             unsigned short* __restrict__ adjnb,
                                             unsigned short* __restrict__ WlT,
                                             unsigned short* __restrict__ Wl1T) {
  __shared__ float tile[64][65];
  const int bid = blockIdx.x;
  if (bid < ANB) {
    const int w = threadIdx.x >> 6;
    const int hl = (threadIdx.x >> 5) & 1;
    const int l = threadIdx.x & 31;
    const int row = bid * 8 + w * 2 + hl;
    const float4* a = reinterpret_cast<const float4*>(adj + (size_t)row * DD);
    float4 v[6];
    #pragma unroll
    for (int i = 0; i < 3; ++i) {
      int u = l + i * 32;
      v[2 * i]     = a[u * 2];
      v[2 * i + 1] = a[u * 2 + 1];
    }
    float s = 0.f;
    #pragma unroll
    for (int i = 0; i < 6; ++i) s += (v[i].x + v[i].y) + (v[i].z + v[i].w);
    #pragma unroll
    for (int off = 16; off; off >>= 1) s += __shfl_xor(s, off);
    float rinv = (s == 0.f) ? 0.f : 1.f / s;
    u16x8* o = reinterpret_cast<u16x8*>(adjnb + (size_t)row * DD);
    #pragma unroll
    for (int i = 0; i < 3; ++i) {
      float4 p = v[2 * i], q = v[2 * i + 1];
      p.x *= rinv; p.y *= rinv; p.z *= rinv; p.w *= rinv;
      q.x *= rinv; q.y *= rinv; q.z *= rinv; q.w *= rinv;
      o[l + i * 32] = pack8(p, q);
    }
  } else {
    const int tb = bid - ANB;
    const int tr = tb / 12, tc = tb % 12;
    const int c = threadIdx.x & 63, r0 = threadIdx.x >> 6;
    const float* srcs[2] = {Wl, Wl1};
    unsigned short* dsts[2] = {WlT, Wl1T};
    #pragma unroll
    for (int m = 0; m < 2; ++m) {
      const float* src = srcs[m];
      #pragma unroll
      for (int i = 0; i < 16; ++i) {
        int r = r0 + i * 4;
        tile[r][c] = src[(size_t)(tr * 64 + r) * DD + tc * 64 + c];
      }
      __syncthreads();
      unsigned short* dst = dsts[m];
      #pragma unroll
      for (int i = 0; i < 16; ++i) {
        int r2 = r0 + i * 4;
        dst[(size_t)(tc * 64 + r2) * DD + tr * 64 + c] = f2bf(tile[c][r2]);
      }
      __syncthreads();
    }
  }
}

// ------- 256x256 BK=64 8-wave 8-phase GEMM (m201-template port) -------
// 8 waves (2M x 4N), wave tile 128x64, quadrant/phase = 64x32 = 16 MFMA.
// LDS 128KB: buf b in {0,1}: A = b*65536 (256 rows x 128B), B = +32768.
// Half-tile rotation (provably race-free, all read lags >= 3 stage-ops):
//   tile t phases: q0 stages Bh0(t+1), q1 Bh1(t+1)  [B buf (t+1)&1 free
//   since tile t-1's B reads done], q2 stages Ah0(t+2), q3 Ah1(t+2)
//   [into buf t&1's A region: tile t's A reads completed by end of q1].
// Uniform s_waitcnt vmcnt(4) per phase (2 halves outstanding; never 0).
// Phase: {ds_reads; stage; vmcnt(4); barrier; setprio1; 16 MFMA; setprio0;
// barrier}. Quadrant walk Q00->Q10->Q11->Q01 (a0 held, peak frags 80 VGPR).
// Swizzle: 16B slot ^= row&7, pre-applied on global source (gload_lds dest
// linear); frag read slot = (kh*4+ks)^(row&7) -> 2 lanes/bank (free).
// MODE 0: e1 = Xb @ W1T, transposed bf16 store (NT=12)
// MODE 1: out = leaky( adjnb@e1 + Xb@Wl ), fused 24-tile K-loop, fp32 store

template<int MODE>
__global__ __launch_bounds__(512) void gemm8p(
    const unsigned short* __restrict__ P0,  // MODE0: Xb     MODE1: adjnb
    const unsigned short* __restrict__ P1,  // MODE0: W1T    MODE1: e1T
    const unsigned short* __restrict__ P2,  // MODE1: Xb
    const unsigned short* __restrict__ P3,  // MODE1: WlT
    void* __restrict__ outp)
{
  __shared__ char smem[131072];
  constexpr int NT = MODE ? 24 : 12;
  const int tid = threadIdx.x, lane = tid & 63;
  const int wid = tid >> 6;
  const int wr = wid >> 2, wc = wid & 3;      // wave tile 128x64

  // XCD-chunked bijective logical id (grid 288 = 8 XCD x 36)
  const int logical = (blockIdx.x & 7) * 36 + (blockIdx.x >> 3);

  const unsigned short *Ag0, *Bg0, *Ag1 = nullptr, *Bg1 = nullptr;
  int mt, nt, b;
  if (MODE == 0) {
    mt = logical / 3; nt = logical % 3;       // mt 0..95 (nt inner: A-panel shared)
    b = mt / 3;
    Ag0 = P0 + (size_t)mt * 256 * DD;
    Bg0 = P1 + (size_t)nt * 256 * DD;
  } else {
    b = logical / 9; int r = logical % 9; mt = r / 3; nt = r % 3;
    size_t bo = (size_t)b * BE;
    Ag0 = P0 + bo + (size_t)mt * 256 * DD;    // adjnb
    Bg0 = P1 + bo + (size_t)nt * 256 * DD;    // e1T
    Ag1 = P2 + bo + (size_t)mt * 256 * DD;    // Xb
    Bg1 = P3 + (size_t)nt * 256 * DD;         // WlT
  }

  const int srow_t = tid >> 3;                // 0..63 (row within 64-row G-load)
  const int sslot = tid & 7;                  // phys 16B slot

  // stage one 128-row half-tile (2 x 8KB G-loads, 2 loads/thread)
  auto stage = [&](int s, bool isA, int hi) {
    int sc = s < NT ? s : 0;                  // clamp keeps vmcnt uniform
    int kk; const unsigned short* base;
    if (MODE == 1 && sc >= 12) { kk = sc - 12; base = isA ? Ag1 : Bg1; }
    else                       { kk = sc;      base = isA ? Ag0 : Bg0; }
    char* region = smem + (s & 1) * 65536 + (isA ? 0 : 32768) + hi * 16384;
    #pragma unroll
    for (int l = 0; l < 2; ++l) {
      int row = hi * 128 + l * 64 + srow_t;
      const unsigned short* src = base + (size_t)row * DD + kk * 64
                                  + (sslot ^ (row & 7)) * 8;
      __builtin_amdgcn_global_load_lds(
          (const __attribute__((address_space(1))) void*)src,
          (__attribute__((address_space(3))) void*)(region + l * 8192 + wid * 1024),
          16, 0, 0);
    }
  };

  const int ks = lane >> 4;                   // k-slot 0..3
  const int l15 = lane & 15;
  auto rdA = [&](int bufo, int rh, int fi, int kh) -> bf16x8 {
    int row = wr * 128 + rh * 64 + fi * 16 + l15;
    int slot = (kh * 4 + ks) ^ (row & 7);
    return *reinterpret_cast<const bf16x8*>(smem + bufo + row * 128 + slot * 16);
  };
  auto rdB = [&](int bufo, int ch, int fj, int kh) -> bf16x8 {
    int row = wc * 64 + ch * 32 + fj * 16 + l15;
    int slot = (kh * 4 + ks) ^ (row & 7);
    return *reinterpret_cast<const bf16x8*>(smem + bufo + 32768 + row * 128 + slot * 16);
  };

  f32x4 acc[8][4] = {};
  bf16x8 a0[8], a1[8], b0[4], b1[4];

  // prologue: A(t0), B(t0), A(t1)  [6 halves]; t0 landed after vmcnt(4)
  stage(0, true, 0); stage(0, true, 1);
  stage(0, false, 0); stage(0, false, 1);
  stage(1, true, 0); stage(1, true, 1);
  asm volatile("s_waitcnt vmcnt(4)" ::: "memory");
  __builtin_amdgcn_s_barrier();

  for (int t = 0; t < NT; ++t) {
    const int bufo = (t & 1) * 65536;

    // ---- q0: Q(0,0) ----
    #pragma unroll
    for (int fi = 0; fi < 4; ++fi) {
      a0[fi * 2]     = rdA(bufo, 0, fi, 0);
      a0[fi * 2 + 1] = rdA(bufo, 0, fi, 1);
    }
    #pragma unroll
    for (int fj = 0; fj < 2; ++fj) {
      b0[fj * 2]     = rdB(bufo, 0, fj, 0);
      b0[fj * 2 + 1] = rdB(bufo, 0, fj, 1);
    }
    stage(t + 1, false, 0);
    asm volatile("s_waitcnt vmcnt(4)" ::: "memory");
    __builtin_amdgcn_s_barrier();
    __builtin_amdgcn_s_setprio(1);
    #pragma unroll
    for (int kh = 0; kh < 2; ++kh)
      #pragma unroll
      for (int fi = 0; fi < 4; ++fi)
        #pragma unroll
        for (int fj = 0; fj < 2; ++fj)
          acc[fi][fj] = __builtin_amdgcn_mfma_f32_16x16x32_bf16(
              a0[fi * 2 + kh], b0[fj * 2 + kh], acc[fi][fj], 0, 0, 0);
    __builtin_amdgcn_s_setprio(0);
    __builtin_amdgcn_s_barrier();

    // ---- q1: Q(1,0) ----
    #pragma unroll
    for (int fi = 0; fi < 4; ++fi) {
      a1[fi * 2]     = rdA(bufo, 1, fi, 0);
      a1[fi * 2 + 1] = rdA(bufo, 1, fi, 1);
    }
    stage(t + 1, false, 1);
    asm volatile("s_waitcnt vmcnt(4)" ::: "memory");
    __builtin_amdgcn_s_barrier();
    __builtin_amdgcn_s_setprio(1);
    #pragma unroll
    for (int kh = 0; kh < 2; ++kh)
      #pragma unroll
      for (int fi = 0; fi < 4; ++fi)
        #pragma unroll
        for (int fj = 0; fj < 2; ++fj)
          acc[4 + fi][fj] = __builtin_amdgcn_mfma_f32_16x16x32_bf16(
              a1[fi * 2 + kh], b0[fj * 2 + kh], acc[4 + fi][fj], 0, 0, 0);
    __builtin_amdgcn_s_setprio(0);
    __builtin_amdgcn_s_barrier();

    // ---- q2: Q(1,1) ----
    #pragma unroll
    for (int fj = 0; fj < 2; ++fj) {
      b1[fj * 2]     = rdB(bufo, 1, fj, 0);
      b1[fj * 2 + 1] = rdB(bufo, 1, fj, 1);
    }
    stage(t + 2, true, 0);                    // into buf[t&1].A (reads done by q1)
    asm volatile("s_waitcnt vmcnt(4)" ::: "memory");
    __builtin_amdgcn_s_barrier();
    __builtin_amdgcn_s_setprio(1);
    #pragma unroll
    for (int kh = 0; kh < 2; ++kh)
      #pragma unroll
      for (int fi = 0; fi < 4; ++fi)
        #pragma unroll
        for (int fj = 0; fj < 2; ++fj)
          acc[4 + fi][2 + fj] = __builtin_amdgcn_mfma_f32_16x16x32_bf16(
              a1[fi * 2 + kh], b1[fj * 2 + kh], acc[4 + fi][2 + fj], 0, 0, 0);
    __builtin_amdgcn_s_setprio(0);
    __builtin_amdgcn_s_barrier();

    // ---- q3: Q(0,1) ----
    stage(t + 2, true, 1);
    asm volatile("s_waitcnt vmcnt(4)" ::: "memory");
    __builtin_amdgcn_s_barrier();
    __builtin_amdgcn_s_setprio(1);
    #pragma unroll
    for (int kh = 0; kh < 2; ++kh)
      #pragma unroll
      for (int fi = 0; fi < 4; ++fi)
        #pragma unroll
        for (int fj = 0; fj < 2; ++fj)
          acc[fi][2 + fj] = __builtin_amdgcn_mfma_f32_16x16x32_bf16(
              a0[fi * 2 + kh], b1[fj * 2 + kh], acc[fi][2 + fj], 0, 0, 0);
    __builtin_amdgcn_s_setprio(0);
    __builtin_amdgcn_s_barrier();
  }
  asm volatile("s_waitcnt vmcnt(0)" ::: "memory");   // drain dummy stages

  // ---------------- epilogue ----------------
  if (MODE == 0) {
    unsigned short* ob = (unsigned short*)outp + (size_t)b * BE;
    const int mloc = (mt % 3) * 256 + wr * 128 + (lane >> 4) * 4;
    #pragma unroll
    for (int mi = 0; mi < 8; ++mi)
      #pragma unroll
      for (int ni = 0; ni < 4; ++ni) {
        int m = mloc + mi * 16;
        int d = nt * 256 + wc * 64 + ni * 16 + l15;
        f32x4 v = acc[mi][ni];
        ushort4 o;
        o.x = f2bf(v[0]); o.y = f2bf(v[1]); o.z = f2bf(v[2]); o.w = f2bf(v[3]);
        *reinterpret_cast<ushort4*>(ob + (size_t)d * DD + m) = o;  // e1T[d][m..m+3]
      }
  } else {
    float* ob = (float*)outp + (size_t)b * BE;
    const int mloc = mt * 256 + wr * 128 + (lane >> 4) * 4;
    #pragma unroll
    for (int mi = 0; mi < 8; ++mi)
      #pragma unroll
      for (int ni = 0; ni < 4; ++ni) {
        int m = mloc + mi * 16;
        int n = nt * 256 + wc * 64 + ni * 16 + l15;
        f32x4 v = acc[mi][ni];
        #pragma unroll
        for (int j = 0; j < 4; ++j) {
          float x = v[j];
          ob[(size_t)(m + j) * DD + n] = x > 0.f ? x : 0.01f * x;
        }
      }
  }
}

// ---------------- launch ----------------

extern "C" void kernel_launch(void* const* d_in, const int* in_sizes, int n_in,
                              void* d_out, int out_size, void* d_ws, size_t ws_size,
                              hipStream_t stream) {
  const float* X   = (const float*)d_in[0];
  const float* adj = (const float*)d_in[1];
  const float* Wl  = (const float*)d_in[2];
  const float* Wl1 = (const float*)d_in[3];
  float* out = (float*)d_out;

  char* ws = (char*)d_ws;
  const size_t SZ = (size_t)BN_ROWS * DD * 2;   // 37,748,736 bytes
  unsigned short* Xb    = (unsigned short*)(ws);
  unsigned short* adjnb = (unsigned short*)(ws + SZ);
  unsigned short* e1T   = (unsigned short*)(ws + 2 * SZ);
  unsigned short* WlT   = (unsigned short*)(ws + 3 * SZ);
  unsigned short* Wl1T  = (unsigned short*)(ws + 3 * SZ + (size_t)BE * 2);

  convertX<<<CXB, 256, 0, stream>>>(X, Xb);
  prep2<<<ANB + 144, 256, 0, stream>>>(adj, Wl, Wl1, adjnb, WlT, Wl1T);
  gemm8p<0><<<288, 512, 0, stream>>>(Xb, Wl1T, nullptr, nullptr, e1T);
  gemm8p<1><<<288, 512, 0, stream>>>(adjnb, e1T, Xb, WlT, out);
}

// Round 13
// 139.038 us; speedup vs baseline: 1.4059x; 1.4059x over previous
//
#include <hip/hip_runtime.h>
#include <hip/hip_bf16.h>
#include <cstdint>
#include <cstddef>

// Problem constants: B=32, N=768, D=768
#define BN_ROWS 24576
#define DD 768
#define BE (768*768)
#define BM 192
#define BN_T 192
#define BK 32
#define ABUF 12288            // gemm_e1: A region bytes per buffer
#define BUFSZ 24576           // gemm_e1: A+B per buffer

typedef __attribute__((ext_vector_type(8))) short bf16x8;
typedef __attribute__((ext_vector_type(4))) float f32x4;
typedef __attribute__((ext_vector_type(8))) unsigned short u16x8;

static __device__ __forceinline__ unsigned short f2bf(float f) {
  unsigned int u = __builtin_bit_cast(unsigned int, f);
  unsigned int lsb = (u >> 16) & 1u;
  u += 0x7fffu + lsb;
  return (unsigned short)(u >> 16);
}

// Frag-linear layout for a 768(col) x 768(k) bf16 B-matrix:
//   block f = (col>>4)*24 + (k>>5), 512 elems each;
//   elem addr = f*512 + ((col&15) + (((k>>3)&3)<<4))*8 + (k&7)
// A wave's 16x32 B-fragment = one contiguous 1KB block, lane l at l*16B.

// ---------------- fused prep kernel ----------------
// [0,4096)        convertX (grid-stride float4->ushort4)
// [4096,4240)     Wl1 -> Wl1T row-major transpose (LDS tiles; gemm_e1 B)
// [4240,4528)     Wl  -> WlT frag-linear (coalesced; gemm_bg B)
// [4528,10672)    adjNorm (4 rows/block)

#define PREP_CX 4096
#define PREP_WT 144
#define PREP_FL 288
#define PREP_AN 6144

__global__ __launch_bounds__(256) void prep(const float* __restrict__ X,
                                            const float* __restrict__ adj,
                                            const float* __restrict__ Wl,
                                            const float* __restrict__ Wl1,
                                            unsigned short* __restrict__ Xb,
                                            unsigned short* __restrict__ adjnb,
                                            unsigned short* __restrict__ WlT,
                                            unsigned short* __restrict__ Wl1T) {
  __shared__ float tile[64][65];
  const int bid = blockIdx.x;

  if (bid < PREP_CX) {
    const int n4 = (BN_ROWS * DD) / 4;
    for (int i = bid * 256 + threadIdx.x; i < n4; i += PREP_CX * 256) {
      float4 v = reinterpret_cast<const float4*>(X)[i];
      ushort4 o;
      o.x = f2bf(v.x); o.y = f2bf(v.y); o.z = f2bf(v.z); o.w = f2bf(v.w);
      reinterpret_cast<ushort4*>(Xb)[i] = o;
    }
  } else if (bid < PREP_CX + PREP_WT) {
    const int tb = bid - PREP_CX;
    const int tr = tb / 12, tc = tb % 12;
    const int c = threadIdx.x & 63, r0 = threadIdx.x >> 6;
    #pragma unroll
    for (int i = 0; i < 16; ++i) {
      int r = r0 + i * 4;
      tile[r][c] = Wl1[(size_t)(tr * 64 + r) * DD + tc * 64 + c];
    }
    __syncthreads();
    #pragma unroll
    for (int i = 0; i < 16; ++i) {
      int r2 = r0 + i * 4;
      Wl1T[(size_t)(tc * 64 + r2) * DD + tr * 64 + c] = f2bf(tile[c][r2]);
    }
  } else if (bid < PREP_CX + PREP_WT + PREP_FL) {
    // Wl -> WlT frag-linear. wave handles fixed d0 (8 k-rows), 64 e-cols.
    const int b2 = bid - (PREP_CX + PREP_WT);
    const int wg = b2 * 4 + (threadIdx.x >> 6);   // 0..1151
    const int lane = threadIdx.x & 63;
    const int d0 = (wg % 96) * 8;
    const int e = (wg / 96) * 64 + lane;
    u16x8 o;
    #pragma unroll
    for (int j = 0; j < 8; ++j)
      o[j] = f2bf(Wl[(size_t)(d0 + j) * DD + e]);   // coalesced 256B per j
    const int base = ((e >> 4) * 24 + (d0 >> 5)) * 512
                   + ((e & 15) + (((d0 >> 3) & 3) << 4)) * 8;
    *reinterpret_cast<u16x8*>(WlT + base) = o;      // coalesced 16B stores
  } else {
    const int rb = bid - (PREP_CX + PREP_WT + PREP_FL);
    const int wid = threadIdx.x >> 6, lane = threadIdx.x & 63;
    const int row = rb * 4 + wid;
    const float4* a = reinterpret_cast<const float4*>(adj + (size_t)row * DD);
    float4 v[3];
    float s = 0.f;
    #pragma unroll
    for (int i = 0; i < 3; ++i) {
      v[i] = a[i * 64 + lane];
      s += (v[i].x + v[i].y) + (v[i].z + v[i].w);
    }
    #pragma unroll
    for (int off = 32; off; off >>= 1) s += __shfl_down(s, off);
    s = __shfl(s, 0);
    float rinv = (s == 0.f) ? 0.f : 1.f / s;
    ushort4* o = reinterpret_cast<ushort4*>(adjnb + (size_t)row * DD);
    #pragma unroll
    for (int i = 0; i < 3; ++i) {
      ushort4 u;
      u.x = f2bf(v[i].x * rinv); u.y = f2bf(v[i].y * rinv);
      u.z = f2bf(v[i].z * rinv); u.w = f2bf(v[i].w * rinv);
      o[i * 64 + lane] = u;
    }
  }
}

// ----- gemm_e1: 192x192 dbuf LDS GEMM (R9 structure, proven 33us) -----
// e1 = Xb @ W1T(row-major); epilogue NOW writes e1T in FRAG-LINEAR layout.
__global__ __launch_bounds__(256, 2) void gemm_e1(
    const unsigned short* __restrict__ Xb,
    const unsigned short* __restrict__ W1T,
    unsigned short* __restrict__ e1T)
{
  __shared__ char smem[2 * BUFSZ];
  constexpr int NT = 24;
  const int tid = threadIdx.x, lane = tid & 63;
  const int wid = tid >> 6;
  const int wr = wid >> 1, wc = wid & 1;

  const int logical = (blockIdx.x & 7) * 64 + (blockIdx.x >> 3);
  const int mt = logical >> 2, nt = logical & 3;
  const int b = mt >> 2;
  const unsigned short* Ab0 = Xb + (size_t)mt * BM * DD;
  const unsigned short* Bb0 = W1T + (size_t)nt * BN_T * DD;

  const int r_in = lane >> 2;
  const int s_in = lane & 3;

  auto stage = [&](int s) {
    const int buf = (s & 1) * BUFSZ;
    #pragma unroll
    for (int i = 0; i < 6; ++i) {
      int chunk = wid * 6 + i;
      bool isA = chunk < 12;
      int c = isA ? chunk : chunk - 12;
      int row = c * 16 + r_in;
      int slot = s_in ^ ((row >> 1) & 3);
      const unsigned short* src = (isA ? Ab0 : Bb0) + (size_t)row * DD + s * BK + slot * 8;
      __builtin_amdgcn_global_load_lds(
          (const __attribute__((address_space(1))) void*)src,
          (__attribute__((address_space(3))) void*)(smem + buf + (isA ? 0 : ABUF) + c * 1024),
          16, 0, 0);
    }
  };

  const int ks = lane >> 4;
  auto frag = [&](int off, int row) -> bf16x8 {
    int slot = ks ^ ((row >> 1) & 3);
    return *reinterpret_cast<const bf16x8*>(smem + off + row * 64 + slot * 16);
  };

  f32x4 acc[6][6] = {};
  const int arow = wr * 96 + (lane & 15);
  const int brow = wc * 96 + (lane & 15);

  stage(0);
  for (int t = 0; t < NT; ++t) {
    asm volatile("s_waitcnt vmcnt(0)" ::: "memory");
    __builtin_amdgcn_s_barrier();
    if (t + 1 < NT) stage(t + 1);
    const int bufA = (t & 1) * BUFSZ;
    const int bufB = bufA + ABUF;
    bf16x8 a[6], bg[6];
    #pragma unroll
    for (int i = 0; i < 6; ++i) a[i] = frag(bufA, arow + i * 16);
    #pragma unroll
    for (int i = 0; i < 6; ++i) bg[i] = frag(bufB, brow + i * 16);
    __builtin_amdgcn_s_setprio(1);
    #pragma unroll
    for (int ni = 0; ni < 6; ++ni)
      #pragma unroll
      for (int mi = 0; mi < 6; ++mi)
        acc[mi][ni] = __builtin_amdgcn_mfma_f32_16x16x32_bf16(a[mi], bg[ni], acc[mi][ni], 0, 0, 0);
    __builtin_amdgcn_s_setprio(0);
  }

  // epilogue: frag-linear e1T  (col=d, k=m)
  unsigned short* ob = e1T + (size_t)b * BE;
  const int m0 = (mt & 3) * BM + wr * 96 + (lane >> 4) * 4;
  const int l15 = lane & 15;
  #pragma unroll
  for (int mi = 0; mi < 6; ++mi)
    #pragma unroll
    for (int ni = 0; ni < 6; ++ni) {
      int m = m0 + mi * 16;
      int cb = nt * 12 + wc * 6 + ni;              // d>>4
      int fa = (cb * 24 + (m >> 5)) * 512
             + (l15 + (((m >> 3) & 3) << 4)) * 8 + (m & 7);
      f32x4 v = acc[mi][ni];
      ushort4 o;
      o.x = f2bf(v[0]); o.y = f2bf(v[1]); o.z = f2bf(v[2]); o.w = f2bf(v[3]);
      *reinterpret_cast<ushort4*>(ob + fa) = o;
    }
}

// ----- gemm_bg: 192x192, A via LDS (12KB dbuf), B DIRECT global->VGPR -----
// out = leaky( adjnb@e1 + Xb@Wl ), fused 48-tile K-loop.
// Per tile: vmcnt(6) [A landed, B(t) landed long ago, B(t+1) stays in
// flight]; barrier; stage A(t+1) 3 gload_lds; load B(t+1) 6 frag loads
// (compiler-tracked); ds_read a-halves; 36 MFMA. B regs double-buffered
// via static even/odd unroll (rule #20).
__global__ __launch_bounds__(256, 2) void gemm_bg(
    const unsigned short* __restrict__ adjnb,
    const unsigned short* __restrict__ e1T,
    const unsigned short* __restrict__ Xb,
    const unsigned short* __restrict__ WlT,
    float* __restrict__ out)
{
  __shared__ char smem[24576];               // A only: 2 x 12KB
  constexpr int NT = 48;
  const int tid = threadIdx.x, lane = tid & 63;
  const int wid = tid >> 6;
  const int wr = wid >> 1, wc = wid & 1;

  const int logical = (blockIdx.x & 7) * 64 + (blockIdx.x >> 3);
  const int b = logical >> 4;
  const int r = logical & 15;
  const int mt = r >> 2, nt = r & 3;
  const size_t bo = (size_t)b * BE;
  const unsigned short* A0 = adjnb + bo + (size_t)mt * BM * DD;
  const unsigned short* A1 = Xb + bo + (size_t)mt * BM * DD;
  const unsigned short* B0 = e1T + bo;       // frag-linear
  const unsigned short* B1 = WlT;            // frag-linear

  const int r_in = lane >> 2;
  const int s_in = lane & 3;
  const int colblk0 = nt * 12 + wc * 6;

  auto stage = [&](int s) {                  // A only: 3 loads/thread
    int sc = s < NT ? s : 0;
    const unsigned short* base = (sc >= 24) ? A1 : A0;
    int kk = (sc >= 24) ? sc - 24 : sc;
    const int buf = (s & 1) * 12288;
    #pragma unroll
    for (int i = 0; i < 3; ++i) {
      int chunk = wid * 3 + i;
      int row = chunk * 16 + r_in;
      int slot = s_in ^ ((row >> 1) & 3);
      const unsigned short* src = base + (size_t)row * DD + kk * BK + slot * 8;
      __builtin_amdgcn_global_load_lds(
          (const __attribute__((address_space(1))) void*)src,
          (__attribute__((address_space(3))) void*)(smem + buf + chunk * 1024),
          16, 0, 0);
    }
  };

  auto loadB = [&](int s, bf16x8* dst) {     // 6 coalesced 16B/lane loads
    int sc = s < NT ? s : 0;
    const unsigned short* base = (sc >= 24) ? B1 : B0;
    int kk = (sc >= 24) ? sc - 24 : sc;
    #pragma unroll
    for (int ni = 0; ni < 6; ++ni)
      dst[ni] = *reinterpret_cast<const bf16x8*>(
          base + ((colblk0 + ni) * 24 + kk) * 512 + lane * 8);
  };

  const int ks = lane >> 4;
  auto rdA = [&](int off, int row) -> bf16x8 {
    int slot = ks ^ ((row >> 1) & 3);
    return *reinterpret_cast<const bf16x8*>(smem + off + row * 64 + slot * 16);
  };

  f32x4 acc[6][6] = {};
  const int arow = wr * 96 + (lane & 15);
  bf16x8 bA[6], bB[6];

  auto body = [&](int bufo, bf16x8* bfr) {
    #pragma unroll
    for (int mh = 0; mh < 2; ++mh) {
      bf16x8 a[3];
      #pragma unroll
      for (int i = 0; i < 3; ++i) a[i] = rdA(bufo, arow + mh * 48 + i * 16);
      __builtin_amdgcn_s_setprio(1);
      #pragma unroll
      for (int mi = 0; mi < 3; ++mi)
        #pragma unroll
        for (int ni = 0; ni < 6; ++ni)
          acc[mh * 3 + mi][ni] = __builtin_amdgcn_mfma_f32_16x16x32_bf16(
              a[mi], bfr[ni], acc[mh * 3 + mi][ni], 0, 0, 0);
      __builtin_amdgcn_s_setprio(0);
    }
  };

  stage(0); loadB(0, bA);
  for (int t = 0; t < NT; t += 2) {
    asm volatile("s_waitcnt vmcnt(6)" ::: "memory");   // A(t) staged; B in flight
    __builtin_amdgcn_s_barrier();
    stage(t + 1); loadB(t + 1, bB);
    body(0, bA);
    asm volatile("s_waitcnt vmcnt(6)" ::: "memory");
    __builtin_amdgcn_s_barrier();
    stage(t + 2); loadB(t + 2, bA);
    body(12288, bB);
  }
  asm volatile("s_waitcnt vmcnt(0)" ::: "memory");     // drain tail dummies

  float* ob = out + bo;
  const int m0 = mt * BM + wr * 96 + (lane >> 4) * 4;
  const int l15 = lane & 15;
  #pragma unroll
  for (int mi = 0; mi < 6; ++mi)
    #pragma unroll
    for (int ni = 0; ni < 6; ++ni) {
      int m = m0 + mi * 16;
      int n = nt * BN_T + wc * 96 + ni * 16 + l15;
      f32x4 v = acc[mi][ni];
      #pragma unroll
      for (int j = 0; j < 4; ++j) {
        float x = v[j];
        ob[(size_t)(m + j) * DD + n] = x > 0.f ? x : 0.01f * x;
      }
    }
}

// ---------------- launch ----------------

extern "C" void kernel_launch(void* const* d_in, const int* in_sizes, int n_in,
                              void* d_out, int out_size, void* d_ws, size_t ws_size,
                              hipStream_t stream) {
  const float* X   = (const float*)d_in[0];
  const float* adj = (const float*)d_in[1];
  const float* Wl  = (const float*)d_in[2];
  const float* Wl1 = (const float*)d_in[3];
  float* out = (float*)d_out;

  char* ws = (char*)d_ws;
  const size_t SZ = (size_t)BN_ROWS * DD * 2;   // 37,748,736 bytes
  unsigned short* Xb    = (unsigned short*)(ws);
  unsigned short* adjnb = (unsigned short*)(ws + SZ);
  unsigned short* e1T   = (unsigned short*)(ws + 2 * SZ);
  unsigned short* WlT   = (unsigned short*)(ws + 3 * SZ);               // frag-linear
  unsigned short* Wl1T  = (unsigned short*)(ws + 3 * SZ + (size_t)BE * 2); // row-major

  prep<<<PREP_CX + PREP_WT + PREP_FL + PREP_AN, 256, 0, stream>>>(
      X, adj, Wl, Wl1, Xb, adjnb, WlT, Wl1T);
  gemm_e1<<<512, 256, 0, stream>>>(Xb, Wl1T, e1T);
  gemm_bg<<<512, 256, 0, stream>>>(adjnb, e1T, Xb, WlT, out);
}

// Round 14
// 135.684 us; speedup vs baseline: 1.4406x; 1.0247x over previous
//
#include <hip/hip_runtime.h>
#include <hip/hip_bf16.h>
#include <cstdint>
#include <cstddef>

// Problem constants: B=32, N=768, D=768
#define BN_ROWS 24576
#define DD 768
#define BE (768*768)
#define BM 192
#define BN_T 192
#define BK 32
#define ABUF 12288
#define BUFSZ 24576

typedef __attribute__((ext_vector_type(8))) short bf16x8;
typedef __attribute__((ext_vector_type(4))) float f32x4;
typedef __attribute__((ext_vector_type(8))) unsigned short u16x8;

static __device__ __forceinline__ unsigned short f2bf(float f) {
  unsigned int u = __builtin_bit_cast(unsigned int, f);
  unsigned int lsb = (u >> 16) & 1u;
  u += 0x7fffu + lsb;
  return (unsigned short)(u >> 16);
}

// cvt via HW instruction (compiler pairs into v_cvt_pk_bf16_f32; RNE)
static __device__ __forceinline__ unsigned short f2bfv(float f) {
  __hip_bfloat16 h = __float2bfloat16(f);
  return __builtin_bit_cast(unsigned short, h);
}

static __device__ __forceinline__ bf16x8 cvt8(float4 u, float4 w, float sc) {
  bf16x8 o;
  o[0] = (short)f2bfv(u.x * sc); o[1] = (short)f2bfv(u.y * sc);
  o[2] = (short)f2bfv(u.z * sc); o[3] = (short)f2bfv(u.w * sc);
  o[4] = (short)f2bfv(w.x * sc); o[5] = (short)f2bfv(w.y * sc);
  o[6] = (short)f2bfv(w.z * sc); o[7] = (short)f2bfv(w.w * sc);
  return o;
}

// ---------------- prep: weight transposes + adj rowsum ----------------
// [0,144):    Wl1 -> Wl1T row-major transpose (gemm_e1 B, gload_lds source)
// [144,432):  Wl  -> WlT frag-linear (gemm_bg B, direct-to-reg source)
// [432,6576): adj rowsum -> rinv[row] (NO adj write; GEMM scales in staging)

#define PREP_WT 144
#define PREP_FL 288
#define PREP_RS 6144

__global__ __launch_bounds__(256) void prep(const float* __restrict__ adj,
                                            const float* __restrict__ Wl,
                                            const float* __restrict__ Wl1,
                                            float* __restrict__ rinv,
                                            unsigned short* __restrict__ WlT,
                                            unsigned short* __restrict__ Wl1T) {
  __shared__ float tile[64][65];
  const int bid = blockIdx.x;
  if (bid < PREP_WT) {
    const int tr = bid / 12, tc = bid % 12;
    const int c = threadIdx.x & 63, r0 = threadIdx.x >> 6;
    #pragma unroll
    for (int i = 0; i < 16; ++i) {
      int r = r0 + i * 4;
      tile[r][c] = Wl1[(size_t)(tr * 64 + r) * DD + tc * 64 + c];
    }
    __syncthreads();
    #pragma unroll
    for (int i = 0; i < 16; ++i) {
      int r2 = r0 + i * 4;
      Wl1T[(size_t)(tc * 64 + r2) * DD + tr * 64 + c] = f2bf(tile[c][r2]);
    }
  } else if (bid < PREP_WT + PREP_FL) {
    const int b2 = bid - PREP_WT;
    const int wg = b2 * 4 + (threadIdx.x >> 6);   // 0..1151
    const int lane = threadIdx.x & 63;
    const int d0 = (wg % 96) * 8;
    const int e = (wg / 96) * 64 + lane;
    u16x8 o;
    #pragma unroll
    for (int j = 0; j < 8; ++j)
      o[j] = f2bf(Wl[(size_t)(d0 + j) * DD + e]);
    const int base = ((e >> 4) * 24 + (d0 >> 5)) * 512
                   + ((e & 15) + (((d0 >> 3) & 3) << 4)) * 8;
    *reinterpret_cast<u16x8*>(WlT + base) = o;
  } else {
    const int rb = bid - (PREP_WT + PREP_FL);
    const int wid = threadIdx.x >> 6, lane = threadIdx.x & 63;
    const int row = rb * 4 + wid;
    const float4* a = reinterpret_cast<const float4*>(adj + (size_t)row * DD);
    float4 v[3];
    float s = 0.f;
    #pragma unroll
    for (int i = 0; i < 3; ++i) {
      v[i] = a[i * 64 + lane];
      s += (v[i].x + v[i].y) + (v[i].z + v[i].w);
    }
    #pragma unroll
    for (int off = 32; off; off >>= 1) s += __shfl_down(s, off);
    if (lane == 0) rinv[row] = (s == 0.f) ? 0.f : 1.f / s;
  }
}

// ----- gemm_e1: 192x192 dbuf, A reg-staged from fp32 X, B via gload_lds -----
// Per tile t: { vmcnt(6)[B(t) landed; A-fp32(t+1) in flight]; barrier;
//   issueB(t+1); ds_read frags(t); 36 MFMA; vmcnt(3)[A-fp32(t+1) landed];
//   cvt+ds_write A(t+1)->buf[(t+1)&1]; issueA(t+2); lgkm(0) }.
// All waits counted; parity separates writes from concurrent readers.
// Epilogue writes e1T FRAG-LINEAR (gemm_bg B source).
__global__ __launch_bounds__(256, 2) void gemm_e1(
    const float* __restrict__ X,
    const unsigned short* __restrict__ W1T,
    unsigned short* __restrict__ e1T)
{
  __shared__ char smem[2 * BUFSZ];
  constexpr int NT = 24;
  const int tid = threadIdx.x, lane = tid & 63;
  const int wid = tid >> 6;
  const int wr = wid >> 1, wc = wid & 1;

  const int logical = (blockIdx.x & 7) * 64 + (blockIdx.x >> 3);
  const int mt = logical >> 2, nt = logical & 3;
  const int b = mt >> 2;
  const float* Ag = X + (size_t)mt * BM * DD;
  const unsigned short* Bg = W1T + (size_t)nt * BN_T * DD;

  const int r_in = lane >> 2;
  const int s_in = lane & 3;

  float4 aR[3][2];
  auto issueA = [&](int s) {
    int kk = s < NT ? s : 0;
    #pragma unroll
    for (int i = 0; i < 3; ++i) {
      int row = (wid * 3 + i) * 16 + r_in;
      int slot = s_in ^ ((row >> 1) & 3);
      const float4* p = reinterpret_cast<const float4*>(
          Ag + (size_t)row * DD + kk * BK + slot * 8);
      aR[i][0] = p[0];
      aR[i][1] = p[1];
    }
  };
  auto writeA = [&](int s) {
    const int buf = (s & 1) * BUFSZ;
    #pragma unroll
    for (int i = 0; i < 3; ++i)
      *reinterpret_cast<bf16x8*>(smem + buf + (wid * 3 + i) * 1024 + lane * 16) =
          cvt8(aR[i][0], aR[i][1], 1.0f);
  };
  auto issueB = [&](int s) {
    int kk = s < NT ? s : 0;
    const int buf = (s & 1) * BUFSZ + ABUF;
    #pragma unroll
    for (int i = 0; i < 3; ++i) {
      int c = wid * 3 + i;
      int row = c * 16 + r_in;
      int slot = s_in ^ ((row >> 1) & 3);
      const unsigned short* src = Bg + (size_t)row * DD + kk * BK + slot * 8;
      __builtin_amdgcn_global_load_lds(
          (const __attribute__((address_space(1))) void*)src,
          (__attribute__((address_space(3))) void*)(smem + buf + c * 1024),
          16, 0, 0);
    }
  };

  const int ks = lane >> 4;
  auto frag = [&](int off, int row) -> bf16x8 {
    int slot = ks ^ ((row >> 1) & 3);
    return *reinterpret_cast<const bf16x8*>(smem + off + row * 64 + slot * 16);
  };

  f32x4 acc[6][6] = {};
  const int arow = wr * 96 + (lane & 15);
  const int brow = wc * 96 + (lane & 15);

  // prologue: in-flight at loop entry = B(0)[3, oldest] + A(1)[6]
  issueA(0);
  asm volatile("s_waitcnt vmcnt(0)" ::: "memory");
  writeA(0);
  issueB(0);
  issueA(1);
  asm volatile("s_waitcnt lgkmcnt(0)" ::: "memory");
  __builtin_amdgcn_s_barrier();

  for (int t = 0; t < NT; ++t) {
    asm volatile("s_waitcnt vmcnt(6)" ::: "memory");   // retire B(t); A(t+1) stays
    __builtin_amdgcn_s_barrier();
    issueB(t + 1);                                     // -> buf[(t+1)&1].B (safe)

    const int bufA = (t & 1) * BUFSZ;
    const int bufB = bufA + ABUF;
    bf16x8 a[6], bg[6];
    #pragma unroll
    for (int i = 0; i < 6; ++i) a[i] = frag(bufA, arow + i * 16);
    #pragma unroll
    for (int i = 0; i < 6; ++i) bg[i] = frag(bufB, brow + i * 16);

    __builtin_amdgcn_s_setprio(1);
    #pragma unroll
    for (int ni = 0; ni < 6; ++ni)
      #pragma unroll
      for (int mi = 0; mi < 6; ++mi)
        acc[mi][ni] = __builtin_amdgcn_mfma_f32_16x16x32_bf16(a[mi], bg[ni], acc[mi][ni], 0, 0, 0);
    __builtin_amdgcn_s_setprio(0);

    asm volatile("s_waitcnt vmcnt(3)" ::: "memory");   // retire A-fp32(t+1)
    writeA(t + 1);                                     // -> buf[(t+1)&1].A (safe)
    issueA(t + 2);                                     // invariant restored
    asm volatile("s_waitcnt lgkmcnt(0)" ::: "memory"); // ds_writes visible pre-barrier
  }

  // epilogue: frag-linear e1T (col=d, k=m)
  unsigned short* ob = e1T + (size_t)b * BE;
  const int m0 = (mt & 3) * BM + wr * 96 + (lane >> 4) * 4;
  const int l15 = lane & 15;
  #pragma unroll
  for (int mi = 0; mi < 6; ++mi)
    #pragma unroll
    for (int ni = 0; ni < 6; ++ni) {
      int m = m0 + mi * 16;
      int cb = nt * 12 + wc * 6 + ni;
      int fa = (cb * 24 + (m >> 5)) * 512
             + (l15 + (((m >> 3) & 3) << 4)) * 8 + (m & 7);
      f32x4 v = acc[mi][ni];
      ushort4 o;
      o.x = f2bf(v[0]); o.y = f2bf(v[1]); o.z = f2bf(v[2]); o.w = f2bf(v[3]);
      *reinterpret_cast<ushort4*>(ob + fa) = o;
    }
}

// ----- gemm_bg: A reg-staged from fp32 (adj*rinv | X), B direct-to-reg -----
// out = leaky( adjn@e1 + X@Wl ), fused 48-tile K-loop. Per half-iter:
// { loadB(t+1)->other regs; ds_read a; 36 MFMA (compiler waits this-B);
//   vmcnt(6)[A-fp32(t+1) retired, B(t+1) in flight]; cvt*scale+ds_write
//   A(t+1)->bufW; issueA(t+2); lgkm(0); barrier }.
__global__ __launch_bounds__(256, 2) void gemm_bg(
    const float* __restrict__ adj,
    const float* __restrict__ X,
    const float* __restrict__ rinv,
    const unsigned short* __restrict__ e1T,
    const unsigned short* __restrict__ WlT,
    float* __restrict__ out)
{
  __shared__ char smem[2 * 12288];
  constexpr int NT = 48;
  const int tid = threadIdx.x, lane = tid & 63;
  const int wid = tid >> 6;
  const int wr = wid >> 1, wc = wid & 1;

  const int logical = (blockIdx.x & 7) * 64 + (blockIdx.x >> 3);
  const int b = logical >> 4;
  const int r = logical & 15;
  const int mt = r >> 2, nt = r & 3;
  const size_t bo = (size_t)b * BE;
  const float* A0 = adj + bo + (size_t)mt * BM * DD;          // fp32 adj panel
  const float* A1 = X + (size_t)(b * 768 + mt * BM) * DD;     // fp32 X panel
  const unsigned short* B0 = e1T + bo;                        // frag-linear
  const unsigned short* B1 = WlT;                             // frag-linear

  const int r_in = lane >> 2;
  const int s_in = lane & 3;
  const int colblk0 = nt * 12 + wc * 6;

  float rinv3[3];
  #pragma unroll
  for (int i = 0; i < 3; ++i)
    rinv3[i] = rinv[b * 768 + mt * BM + (wid * 3 + i) * 16 + r_in];

  float4 aR[3][2];
  auto issueA = [&](int s) {
    int sc = s < NT ? s : 0;
    const float* base = (sc >= 24) ? A1 : A0;
    int kk = (sc >= 24) ? sc - 24 : sc;
    #pragma unroll
    for (int i = 0; i < 3; ++i) {
      int row = (wid * 3 + i) * 16 + r_in;
      int slot = s_in ^ ((row >> 1) & 3);
      const float4* p = reinterpret_cast<const float4*>(
          base + (size_t)row * DD + kk * BK + slot * 8);
      aR[i][0] = p[0];
      aR[i][1] = p[1];
    }
  };
  auto writeA = [&](int s) {
    int sc = s < NT ? s : 0;
    const bool isAdj = sc < 24;
    const int buf = (s & 1) * 12288;
    #pragma unroll
    for (int i = 0; i < 3; ++i) {
      float scl = isAdj ? rinv3[i] : 1.0f;
      *reinterpret_cast<bf16x8*>(smem + buf + (wid * 3 + i) * 1024 + lane * 16) =
          cvt8(aR[i][0], aR[i][1], scl);
    }
  };
  auto loadB = [&](int s, bf16x8* dst) {
    int sc = s < NT ? s : 0;
    const unsigned short* base = (sc >= 24) ? B1 : B0;
    int kk = (sc >= 24) ? sc - 24 : sc;
    #pragma unroll
    for (int ni = 0; ni < 6; ++ni)
      dst[ni] = *reinterpret_cast<const bf16x8*>(
          base + ((colblk0 + ni) * 24 + kk) * 512 + lane * 8);
  };

  const int ks = lane >> 4;
  auto rdA = [&](int off, int row) -> bf16x8 {
    int slot = ks ^ ((row >> 1) & 3);
    return *reinterpret_cast<const bf16x8*>(smem + off + row * 64 + slot * 16);
  };

  f32x4 acc[6][6] = {};
  const int arow = wr * 96 + (lane & 15);
  bf16x8 bA[6], bB[6];

  auto body = [&](int bufo, bf16x8* bfr) {
    #pragma unroll
    for (int mh = 0; mh < 2; ++mh) {
      bf16x8 a[3];
      #pragma unroll
      for (int i = 0; i < 3; ++i) a[i] = rdA(bufo, arow + mh * 48 + i * 16);
      __builtin_amdgcn_s_setprio(1);
      #pragma unroll
      for (int mi = 0; mi < 3; ++mi)
        #pragma unroll
        for (int ni = 0; ni < 6; ++ni)
          acc[mh * 3 + mi][ni] = __builtin_amdgcn_mfma_f32_16x16x32_bf16(
              a[mi], bfr[ni], acc[mh * 3 + mi][ni], 0, 0, 0);
      __builtin_amdgcn_s_setprio(0);
    }
  };

  // prologue
  issueA(0);
  asm volatile("s_waitcnt vmcnt(0)" ::: "memory");
  writeA(0);
  loadB(0, bA);
  issueA(1);
  asm volatile("s_waitcnt lgkmcnt(0)" ::: "memory");
  __builtin_amdgcn_s_barrier();

  for (int t = 0; t < NT; t += 2) {
    // half t (even): read buf0 with bA; write buf1
    loadB(t + 1, bB);
    body(0, bA);
    asm volatile("s_waitcnt vmcnt(6)" ::: "memory");   // A-fp32(t+1) retired
    writeA(t + 1);
    issueA(t + 2);
    asm volatile("s_waitcnt lgkmcnt(0)" ::: "memory");
    __builtin_amdgcn_s_barrier();

    // half t+1 (odd): read buf1 with bB; write buf0
    loadB(t + 2, bA);
    body(12288, bB);
    asm volatile("s_waitcnt vmcnt(6)" ::: "memory");
    writeA(t + 2);
    issueA(t + 3);
    asm volatile("s_waitcnt lgkmcnt(0)" ::: "memory");
    __builtin_amdgcn_s_barrier();
  }

  float* ob = out + bo;
  const int m0 = mt * BM + wr * 96 + (lane >> 4) * 4;
  const int l15 = lane & 15;
  #pragma unroll
  for (int mi = 0; mi < 6; ++mi)
    #pragma unroll
    for (int ni = 0; ni < 6; ++ni) {
      int m = m0 + mi * 16;
      int n = nt * BN_T + wc * 96 + ni * 16 + l15;
      f32x4 v = acc[mi][ni];
      #pragma unroll
      for (int j = 0; j < 4; ++j) {
        float x = v[j];
        ob[(size_t)(m + j) * DD + n] = x > 0.f ? x : 0.01f * x;
      }
    }
}

// ---------------- launch ----------------

extern "C" void kernel_launch(void* const* d_in, const int* in_sizes, int n_in,
                              void* d_out, int out_size, void* d_ws, size_t ws_size,
                              hipStream_t stream) {
  const float* X   = (const float*)d_in[0];
  const float* adj = (const float*)d_in[1];
  const float* Wl  = (const float*)d_in[2];
  const float* Wl1 = (const float*)d_in[3];
  float* out = (float*)d_out;

  char* ws = (char*)d_ws;
  const size_t SZ = (size_t)BN_ROWS * DD * 2;     // 37,748,736 bytes (e1T)
  unsigned short* e1T  = (unsigned short*)(ws);                    // frag-linear
  unsigned short* WlT  = (unsigned short*)(ws + SZ);               // frag-linear
  unsigned short* Wl1T = (unsigned short*)(ws + SZ + (size_t)BE * 2); // row-major
  float* rinv          = (float*)(ws + SZ + 2 * (size_t)BE * 2);

  prep<<<PREP_WT + PREP_FL + PREP_RS, 256, 0, stream>>>(adj, Wl, Wl1, rinv, WlT, Wl1T);
  gemm_e1<<<512, 256, 0, stream>>>(X, Wl1T, e1T);
  gemm_bg<<<512, 256, 0, stream>>>(adj, X, rinv, e1T, WlT, out);
}